// Round 13
// baseline (37.544 us; speedup 1.0000x reference)
//
#include <hip/hip_runtime.h>

// Shapley fusion: L=5 views, C=64 channels, N=128*256 spatial positions.
// f(subset) = relu(b + sum_{l in subset} d[l]) where d[l] = dot(feats[l,:,n], w)
// -- the reference's [M,N,C] subset GEMM collapses to 5 dots per pixel.
// Shapley coef for L=5 by subset size: {-, -0.6, 0.05, 1/30, 0.05, 0.2}.
//
// Round-13: r12 body unchanged (DS-diet reduce-scatter butterfly, redundant
// per-thread lattice, depth-2 register pipeline, nt stores); ONE change:
// NBLK 256 -> 512, NITER 4 -> 2. r12 ran 1 block/CU = 1 wave/SIMD -> zero
// TLP, so the lattice's 31-step serial chain + softmax ran at raw latency,
// ~1us/iter exposed. 2 blocks/CU = 2 waves/SIMD doubles hiding depth for
// both ALU chains and vmcnt waits. Also discriminates: if r12's gain was
// request-order throttling, this regresses (~15.5); if compute-hiding is
// the lever, ~13.5. Pre-committed: >=14.3 -> declare structural plateau.

constexpr int L_VIEWS = 5;
constexpr int C_CH    = 64;
constexpr int NPIX    = 128 * 256;   // 32768
constexpr int NBLK    = 512;         // 2 blocks/CU -> 8 waves/CU
constexpr int NITER   = NPIX / (NBLK * 32);   // 2 sequential windows/block

typedef float floatx4 __attribute__((ext_vector_type(4)));

__global__ __launch_bounds__(256)
void shapley_fusion_kernel(const float* __restrict__ feats,
                           const float* __restrict__ w,
                           const float* __restrict__ bptr,
                           float* __restrict__ out)
{
    const int tid  = threadIdx.x;
    const int h    = tid >> 6;        // wave (0..3): channel 16-group
    const int lane = tid & 63;
    const int n8   = lane & 7;        // n-quad within the 32-n window
    const int cg   = lane >> 3;       // channel pair-group within wave (0..7)
    const int cA   = h * 16 + cg * 2; // this thread's 2 channels
    const int cB   = cA + 1;

    const float w0   = w[cA];
    const float w1   = w[cB];
    const float bias = bptr[0];

    // Double-buffered cross-wave exchange: [buf][wave][n8][cg][l] floats.
    __shared__ float xw[2][4][8][8][L_VIEWS];   // 10 KB

    // ---- Depth-2 register pipeline over NITER sequential windows. ----
    // Window k's base: (k*NBLK + blockIdx.x) * 32 -> iteration k covers a
    // contiguous stretch across all blocks (compact sweep).
    float4 vaA[L_VIEWS][2], vaB[L_VIEWS][2];    // two window buffers

    // prologue: load window 0 into A
    {
        const int nq = blockIdx.x * 32 + n8 * 4;
#pragma unroll
        for (int l = 0; l < L_VIEWS; ++l) {
            vaA[l][0] = *reinterpret_cast<const float4*>(
                feats + ((size_t)(l * C_CH + cA) * NPIX + nq));
            vaA[l][1] = *reinterpret_cast<const float4*>(
                feats + ((size_t)(l * C_CH + cB) * NPIX + nq));
        }
    }

#pragma unroll
    for (int k = 0; k < NITER; ++k) {
        const bool useA = (k & 1) == 0;
        const int nq = (k * NBLK + blockIdx.x) * 32 + n8 * 4;

        // Issue next window's loads into the spare buffer (stream overlaps
        // this window's compute; compiler-counted vmcnt keeps them in flight).
        if (k + 1 < NITER) {
            const int nq2 = ((k + 1) * NBLK + blockIdx.x) * 32 + n8 * 4;
            float4 (&vn)[L_VIEWS][2] = useA ? vaB : vaA;
#pragma unroll
            for (int l = 0; l < L_VIEWS; ++l) {
                vn[l][0] = *reinterpret_cast<const float4*>(
                    feats + ((size_t)(l * C_CH + cA) * NPIX + nq2));
                vn[l][1] = *reinterpret_cast<const float4*>(
                    feats + ((size_t)(l * C_CH + cB) * NPIX + nq2));
            }
        }

        const float4 (&va)[L_VIEWS][2] = useA ? vaA : vaB;

        // Serial dots over this thread's 2 channels (zero cross-lane ops).
        float d[L_VIEWS][4];
#pragma unroll
        for (int l = 0; l < L_VIEWS; ++l) {
            d[l][0] = va[l][0].x * w0 + va[l][1].x * w1;
            d[l][1] = va[l][0].y * w0 + va[l][1].y * w1;
            d[l][2] = va[l][0].z * w0 + va[l][1].z * w1;
            d[l][3] = va[l][0].w * w0 + va[l][1].w * w1;
        }

        // Reduce-scatter butterfly over the 8 cg groups (lane bits 3..5):
        // keep only the j-values this thread will own: 10+5+5 = 20 shuffles.
        const bool b0 = (cg & 1) != 0;
        const bool b1 = (cg & 2) != 0;
        float dd[L_VIEWS];
#pragma unroll
        for (int l = 0; l < L_VIEWS; ++l) {
            // round 1 (xor8): keep j with j&1 == cg&1
            const float s0 = b0 ? d[l][0] : d[l][1];
            const float r0 = __shfl_xor(s0, 8, 64);
            const float k0 = (b0 ? d[l][1] : d[l][0]) + r0;   // j pair 0/1
            const float s1 = b0 ? d[l][2] : d[l][3];
            const float r1 = __shfl_xor(s1, 8, 64);
            const float k1 = (b0 ? d[l][3] : d[l][2]) + r1;   // j pair 2/3
            // round 2 (xor16): keep jj == (cg>>1)&1 -> j = cg&3
            const float s2 = b1 ? k0 : k1;
            const float r2 = __shfl_xor(s2, 16, 64);
            float v = (b1 ? k1 : k0) + r2;
            // round 3 (xor32): plain add (both halves need the sum)
            v += __shfl_xor(v, 32, 64);
            dd[l] = v;   // wave-sum over its 16 channels, for j = cg&3
        }

        // Cross-wave exchange (double-buffered; ONE barrier per window).
        const int buf = k & 1;
#pragma unroll
        for (int l = 0; l < L_VIEWS; ++l)
            xw[buf][h][n8][cg][l] = dd[l];
        __syncthreads();

        float dm[L_VIEWS];
#pragma unroll
        for (int l = 0; l < L_VIEWS; ++l) {
            float s = dd[l];
#pragma unroll
            for (int hh = 1; hh < 4; ++hh)
                s += xw[buf][(h + hh) & 3][n8][cg][l];
            dm[l] = s;
        }

        // Gray-code subset walk -> shapley (pixel n = nq + (cg&3); threads
        // with cg&4 duplicate -- VALU slack, saves redistribution DS ops).
        constexpr float WTS[6] = {0.f, -0.6f, 0.05f, 1.0f / 30.0f, 0.05f, 0.2f};
        float S = bias;
        float sh[L_VIEWS] = {0.f, 0.f, 0.f, 0.f, 0.f};
#pragma unroll
        for (int t = 1; t < 32; ++t) {
            const int gm   = t ^ (t >> 1);
            const int bit  = __builtin_ctz(t);
            const bool add = (gm >> bit) & 1;
            S = add ? (S + dm[bit]) : (S - dm[bit]);
            const float f  = fmaxf(S, 0.f);
            const float wt = WTS[__builtin_popcount(gm)];
#pragma unroll
            for (int i = 0; i < L_VIEWS; ++i)
                if (gm & (1 << i)) sh[i] += wt * f;
        }
        float mx = sh[0];
#pragma unroll
        for (int i = 1; i < L_VIEWS; ++i) mx = fmaxf(mx, sh[i]);
        float e[L_VIEWS];
        float sum = 0.f;
#pragma unroll
        for (int i = 0; i < L_VIEWS; ++i) { e[i] = __expf(sh[i] - mx); sum += e[i]; }
        const float inv = 1.f / sum;
        float attn_mine[L_VIEWS];
#pragma unroll
        for (int i = 0; i < L_VIEWS; ++i) attn_mine[i] = e[i] * inv;

        // Redistribute: attn[l][j] from lane n8 + 8*(j + (cg&4)).
        float attn[L_VIEWS][4];
#pragma unroll
        for (int l = 0; l < L_VIEWS; ++l)
#pragma unroll
            for (int j = 0; j < 4; ++j)
                attn[l][j] = __shfl(attn_mine[l], n8 + 8 * (j + (cg & 4)), 64);

        // Fused output straight from registers (no feats re-read).
#pragma unroll
        for (int kk = 0; kk < 2; ++kk) {
            const int c = (kk == 0) ? cA : cB;
            floatx4 acc;
            acc.x = va[0][kk].x * attn[0][0];
            acc.y = va[0][kk].y * attn[0][1];
            acc.z = va[0][kk].z * attn[0][2];
            acc.w = va[0][kk].w * attn[0][3];
#pragma unroll
            for (int l = 1; l < L_VIEWS; ++l) {
                acc.x += va[l][kk].x * attn[l][0];
                acc.y += va[l][kk].y * attn[l][1];
                acc.z += va[l][kk].z * attn[l][2];
                acc.w += va[l][kk].w * attn[l][3];
            }
            __builtin_nontemporal_store(acc,
                reinterpret_cast<floatx4*>(out + (size_t)c * NPIX + nq));
        }
    }
}

extern "C" void kernel_launch(void* const* d_in, const int* in_sizes, int n_in,
                              void* d_out, int out_size, void* d_ws, size_t ws_size,
                              hipStream_t stream) {
    const float* feats = (const float*)d_in[0];   // [5,64,128,256] fp32
    const float* w     = (const float*)d_in[1];   // [64,1] fp32
    const float* b     = (const float*)d_in[2];   // [1] fp32
    float* out         = (float*)d_out;           // [64,128,256] fp32

    // 512 blocks (2/CU, 8 waves/CU) x 256 threads; each sweeps 2 sequential
    // 32-n windows with a depth-2 register pipeline.
    shapley_fusion_kernel<<<NBLK, 256, 0, stream>>>(feats, w, b, out);
}

// Round 14
// 14.673 us; speedup vs baseline: 2.5587x; 2.5587x over previous
//
#include <hip/hip_runtime.h>

// Shapley fusion: L=5 views, C=64 channels, N=128*256 spatial positions.
// f(subset) = relu(b + sum_{l in subset} d[l]) where d[l] = dot(feats[l,:,n], w)
// -- the reference's [M,N,C] subset GEMM collapses to 5 dots per pixel.
// Shapley coef for L=5 by subset size: {-, -0.6, 0.05, 1/30, 0.05, 0.2}.
//
// Round-14: REVERT to r12 verbatim (proven 14.79us best). r13 (NBLK 512 /
// NITER 2, same body) regressed 2.5x -> geometry-constant change tipped
// codegen into a pathology (suspected scratch spill or merged vmcnt waits).
// Session conclusion: every structural attack (occupancy 1-8 waves/SIMD,
// line-aligned/512B-run coalescing, register-resident single-read, DS-pipe
// diet, pipelines depth 1/2, throttled persistent sweep) lands at 14.8-16.7us
// vs the 7.7us naive roofline; the residual is the cache-cold replay stream
// at the machine's effective scattered-read BW (~4.1 TB/s) plus partially
// exposed serial phase -- structural for this harness regime.
//
// Structure (r12): 256 persistent blocks (1/CU) x 4 iterations x depth-2
// register pipeline; serial 2-channel dots; reduce-scatter butterfly (20
// shuffles); 4-wave LDS exchange; redundant per-thread Gray-code lattice;
// shuffle redistribute; nontemporal stores. feats read EXACTLY once.

constexpr int L_VIEWS = 5;
constexpr int C_CH    = 64;
constexpr int NPIX    = 128 * 256;   // 32768
constexpr int NBLK    = 256;         // persistent blocks (1 per CU)
constexpr int NITER   = NPIX / (NBLK * 32);   // 4 sequential windows/block

typedef float floatx4 __attribute__((ext_vector_type(4)));

__global__ __launch_bounds__(256)
void shapley_fusion_kernel(const float* __restrict__ feats,
                           const float* __restrict__ w,
                           const float* __restrict__ bptr,
                           float* __restrict__ out)
{
    const int tid  = threadIdx.x;
    const int h    = tid >> 6;        // wave (0..3): channel 16-group
    const int lane = tid & 63;
    const int n8   = lane & 7;        // n-quad within the 32-n window
    const int cg   = lane >> 3;       // channel pair-group within wave (0..7)
    const int cA   = h * 16 + cg * 2; // this thread's 2 channels
    const int cB   = cA + 1;

    const float w0   = w[cA];
    const float w1   = w[cB];
    const float bias = bptr[0];

    // Double-buffered cross-wave exchange: [buf][wave][n8][cg][l] floats.
    __shared__ float xw[2][4][8][8][L_VIEWS];   // 10 KB

    // ---- Depth-2 register pipeline over NITER sequential windows. ----
    // Window k's base: (k*NBLK + blockIdx.x) * 32  -> iteration k covers a
    // contiguous 8192-n stretch across all blocks (compact sweep).
    float4 vaA[L_VIEWS][2], vaB[L_VIEWS][2];    // two window buffers

    // prologue: load window 0 into A
    {
        const int nq = (0 * NBLK + blockIdx.x) * 32 + n8 * 4;
#pragma unroll
        for (int l = 0; l < L_VIEWS; ++l) {
            vaA[l][0] = *reinterpret_cast<const float4*>(
                feats + ((size_t)(l * C_CH + cA) * NPIX + nq));
            vaA[l][1] = *reinterpret_cast<const float4*>(
                feats + ((size_t)(l * C_CH + cB) * NPIX + nq));
        }
    }

#pragma unroll
    for (int k = 0; k < NITER; ++k) {
        const bool useA = (k & 1) == 0;
        const int nq = (k * NBLK + blockIdx.x) * 32 + n8 * 4;

        // Issue next window's loads into the spare buffer (stream overlaps
        // this window's compute; compiler-counted vmcnt keeps them in flight).
        if (k + 1 < NITER) {
            const int nq2 = ((k + 1) * NBLK + blockIdx.x) * 32 + n8 * 4;
            float4 (&vn)[L_VIEWS][2] = useA ? vaB : vaA;
#pragma unroll
            for (int l = 0; l < L_VIEWS; ++l) {
                vn[l][0] = *reinterpret_cast<const float4*>(
                    feats + ((size_t)(l * C_CH + cA) * NPIX + nq2));
                vn[l][1] = *reinterpret_cast<const float4*>(
                    feats + ((size_t)(l * C_CH + cB) * NPIX + nq2));
            }
        }

        const float4 (&va)[L_VIEWS][2] = useA ? vaA : vaB;

        // Serial dots over this thread's 2 channels (zero cross-lane ops).
        float d[L_VIEWS][4];
#pragma unroll
        for (int l = 0; l < L_VIEWS; ++l) {
            d[l][0] = va[l][0].x * w0 + va[l][1].x * w1;
            d[l][1] = va[l][0].y * w0 + va[l][1].y * w1;
            d[l][2] = va[l][0].z * w0 + va[l][1].z * w1;
            d[l][3] = va[l][0].w * w0 + va[l][1].w * w1;
        }

        // Reduce-scatter butterfly over the 8 cg groups (lane bits 3..5):
        // each round keeps only the j-values this thread will own (20 -> 10
        // -> 5), so 10+5+5 = 20 shuffles instead of a 40-60-op full butterfly.
        const bool b0 = (cg & 1) != 0;
        const bool b1 = (cg & 2) != 0;
        float dd[L_VIEWS];
#pragma unroll
        for (int l = 0; l < L_VIEWS; ++l) {
            // round 1 (xor8): keep j with j&1 == cg&1
            const float s0 = b0 ? d[l][0] : d[l][1];      // send
            const float r0 = __shfl_xor(s0, 8, 64);
            const float k0 = (b0 ? d[l][1] : d[l][0]) + r0;   // j pair 0/1
            const float s1 = b0 ? d[l][2] : d[l][3];
            const float r1 = __shfl_xor(s1, 8, 64);
            const float k1 = (b0 ? d[l][3] : d[l][2]) + r1;   // j pair 2/3
            // round 2 (xor16): keep jj == (cg>>1)&1  -> j = cg&3
            const float s2 = b1 ? k0 : k1;                // send
            const float r2 = __shfl_xor(s2, 16, 64);
            float v = (b1 ? k1 : k0) + r2;
            // round 3 (xor32): plain add (cg bit2 halves both need the sum)
            v += __shfl_xor(v, 32, 64);
            dd[l] = v;   // wave-sum over its 16 channels, for j = cg&3
        }

        // Cross-wave exchange (double-buffered; ONE barrier per window).
        const int buf = k & 1;
#pragma unroll
        for (int l = 0; l < L_VIEWS; ++l)
            xw[buf][h][n8][cg][l] = dd[l];
        __syncthreads();

        float dm[L_VIEWS];
#pragma unroll
        for (int l = 0; l < L_VIEWS; ++l) {
            float s = dd[l];
#pragma unroll
            for (int hh = 1; hh < 4; ++hh)
                s += xw[buf][(h + hh) & 3][n8][cg][l];
            dm[l] = s;
        }

        // Gray-code subset walk -> shapley (for pixel n = nq + (cg&3); threads
        // with cg&4 duplicate -- VALU has slack, saves redistribution DS ops).
        constexpr float WTS[6] = {0.f, -0.6f, 0.05f, 1.0f / 30.0f, 0.05f, 0.2f};
        float S = bias;
        float sh[L_VIEWS] = {0.f, 0.f, 0.f, 0.f, 0.f};
#pragma unroll
        for (int t = 1; t < 32; ++t) {
            const int gm   = t ^ (t >> 1);
            const int bit  = __builtin_ctz(t);
            const bool add = (gm >> bit) & 1;
            S = add ? (S + dm[bit]) : (S - dm[bit]);
            const float f  = fmaxf(S, 0.f);
            const float wt = WTS[__builtin_popcount(gm)];
#pragma unroll
            for (int i = 0; i < L_VIEWS; ++i)
                if (gm & (1 << i)) sh[i] += wt * f;
        }
        float mx = sh[0];
#pragma unroll
        for (int i = 1; i < L_VIEWS; ++i) mx = fmaxf(mx, sh[i]);
        float e[L_VIEWS];
        float sum = 0.f;
#pragma unroll
        for (int i = 0; i < L_VIEWS; ++i) { e[i] = __expf(sh[i] - mx); sum += e[i]; }
        const float inv = 1.f / sum;
        float attn_mine[L_VIEWS];
#pragma unroll
        for (int i = 0; i < L_VIEWS; ++i) attn_mine[i] = e[i] * inv;

        // Redistribute: attn[l][j] from lane n8 + 8*(j + (cg&4)).
        float attn[L_VIEWS][4];
#pragma unroll
        for (int l = 0; l < L_VIEWS; ++l)
#pragma unroll
            for (int j = 0; j < 4; ++j)
                attn[l][j] = __shfl(attn_mine[l], n8 + 8 * (j + (cg & 4)), 64);

        // Fused output straight from registers (no feats re-read).
#pragma unroll
        for (int kk = 0; kk < 2; ++kk) {
            const int c = (kk == 0) ? cA : cB;
            floatx4 acc;
            acc.x = va[0][kk].x * attn[0][0];
            acc.y = va[0][kk].y * attn[0][1];
            acc.z = va[0][kk].z * attn[0][2];
            acc.w = va[0][kk].w * attn[0][3];
#pragma unroll
            for (int l = 1; l < L_VIEWS; ++l) {
                acc.x += va[l][kk].x * attn[l][0];
                acc.y += va[l][kk].y * attn[l][1];
                acc.z += va[l][kk].z * attn[l][2];
                acc.w += va[l][kk].w * attn[l][3];
            }
            __builtin_nontemporal_store(acc,
                reinterpret_cast<floatx4*>(out + (size_t)c * NPIX + nq));
        }
    }
}

extern "C" void kernel_launch(void* const* d_in, const int* in_sizes, int n_in,
                              void* d_out, int out_size, void* d_ws, size_t ws_size,
                              hipStream_t stream) {
    const float* feats = (const float*)d_in[0];   // [5,64,128,256] fp32
    const float* w     = (const float*)d_in[1];   // [64,1] fp32
    const float* b     = (const float*)d_in[2];   // [1] fp32
    float* out         = (float*)d_out;           // [64,128,256] fp32

    // 256 persistent blocks (1/CU) x 256 threads; each sweeps 4 sequential
    // 32-n windows with a depth-2 register pipeline.
    shapley_fusion_kernel<<<NBLK, 256, 0, stream>>>(feats, w, b, out);
}